// Round 11
// baseline (274.322 us; speedup 1.0000x reference)
//
#include <hip/hip_runtime.h>
#include <hip/hip_fp16.h>
#include <stdint.h>

typedef _Float16 f16;
typedef _Float16 f16x8 __attribute__((ext_vector_type(8)));
typedef float    f32x16 __attribute__((ext_vector_type(16)));

#define NEDGE 1000000
#define NT    31250        // 32-edge tiles (31250*32 = 1e6, exact)
#define NTHR  512          // 8 waves/block, 2 waves/SIMD (proven optimum R6/R9/R10)
#define GRID  256
#define GW    (GRID*8)     // 2048 waves

// ---- d_ws layout (bytes); weight frags 1 KB each, sigma-row-permuted ----
#define W1OFF 0                 // 64 frags: f = nt*16+ks
#define W2OFF 65536             // 64 frags: f = nt*8+ks
#define W3OFF 131072            // 32 frags: f = nt*16+ks  (global-streamed)
#define W4OFF 163840            // 4 frags:  f = ks
#define BCOFF 167936            // 14 bias-column frags: W1 nt0..3, W2 nt0..7, W3 nt0..1
#define ZUOFF 182272
#define ZBOFF (ZUOFF + 100000*128*2)
#define WS_FULL (ZBOFF + 100000*128*2)

// sigma: swap bits 2<->3 (involution). Verified R5-R10.
__device__ __forceinline__ int sw23(int i) {
    return (i & 3) | ((i >> 1) & 4) | ((i << 1) & 8) | (i & 16);
}

// ---------------- weight fragment + bias-column builder ----------------
// A-frag (32x32x16 swapped use): lane&31 = row i, k = (lane>>5)*8 + e.
// Weight rows hold neuron n = nt*32 + sw23(i). Bias-column frag: value b[n]
// at k==0 (hi==0, e==0), else 0 -> one MFMA vs 'onef' adds bias to every edge.
__global__ __launch_bounds__(512) void wfrag_kernel(
    const float* __restrict__ W1, const float* __restrict__ b1,
    const float* __restrict__ W2, const float* __restrict__ b2,
    const float* __restrict__ W3, const float* __restrict__ b3,
    const float* __restrict__ W4, float* __restrict__ wsf)
{
    f16* ws = (f16*)wsf;
    const int NF = 178*64;   // 164 weight frags + 14 bias-column frags
    int tid = blockIdx.x*512 + threadIdx.x;
    if (tid >= NF) return;
    int f = tid >> 6, lane = tid & 63;
    int li = lane & 31, hi = lane >> 5;
    int ip = sw23(li);
    f16 v[8];
    if (f < 64) {                       // W1 [128,256]
        int nt = f >> 4, ks = f & 15, n = nt*32 + ip;
        #pragma unroll
        for (int e = 0; e < 8; ++e) v[e] = (f16)W1[n*256 + ks*16 + hi*8 + e];
    } else if (f < 128) {               // W2 [256,128]
        int g = f-64, nt = g >> 3, ks = g & 7, n = nt*32 + ip;
        #pragma unroll
        for (int e = 0; e < 8; ++e) v[e] = (f16)W2[n*128 + ks*16 + hi*8 + e];
    } else if (f < 160) {               // W3 [64,256]
        int g = f-128, nt = g >> 4, ks = g & 15, n = nt*32 + ip;
        #pragma unroll
        for (int e = 0; e < 8; ++e) v[e] = (f16)W3[n*256 + ks*16 + hi*8 + e];
    } else if (f < 164) {               // W4 [5,64], rows >=5 zero, NO sigma
        int ks = f-160;
        #pragma unroll
        for (int e = 0; e < 8; ++e)
            v[e] = (li < 5) ? (f16)W4[li*64 + ks*16 + hi*8 + e] : (f16)0;
    } else {                            // bias columns (sigma-permuted rows)
        int j = f - 164;
        float bv = (j < 4)  ? b1[j*32 + ip]
                 : (j < 12) ? b2[(j-4)*32 + ip]
                            : b3[(j-12)*32 + ip];
        #pragma unroll
        for (int e = 0; e < 8; ++e) v[e] = (f16)0;
        if (hi == 0) v[0] = (f16)bv;
    }
    f16* d = ws + (size_t)f*512 + lane*8;
    #pragma unroll
    for (int e = 0; e < 8; ++e) d[e] = v[e];
}

// ---------------- embedding f32 -> f16 ----------------
__device__ __forceinline__ void cvt8(const float* __restrict__ s, f16* __restrict__ d) {
    float4 a = ((const float4*)s)[0], b = ((const float4*)s)[1];
    union { f16 h[8]; uint4 u; } r;
    r.h[0]=(f16)a.x; r.h[1]=(f16)a.y; r.h[2]=(f16)a.z; r.h[3]=(f16)a.w;
    r.h[4]=(f16)b.x; r.h[5]=(f16)b.y; r.h[6]=(f16)b.z; r.h[7]=(f16)b.w;
    *(uint4*)d = r.u;
}
__global__ __launch_bounds__(512) void ecvt_kernel(
    const float* __restrict__ zu, const float* __restrict__ zb,
    f16* __restrict__ du, f16* __restrict__ db)
{
    const int NPER = 100000*128/8;
    int i = blockIdx.x*512 + threadIdx.x;
    if (i < NPER)          cvt8(zu + (size_t)i*8, du + (size_t)i*8);
    else if (i < 2*NPER) { int j = i - NPER; cvt8(zb + (size_t)j*8, db + (size_t)j*8); }
}

__device__ __forceinline__ unsigned int pkrne(float v0, float v1) {
    union { f16 h[2]; unsigned int u; } r;
    r.h[0] = (f16)v0; r.h[1] = (f16)v1; return r.u;
}

// lane-local epilogue (sigma makes this correct; verified R5-R10)
template<bool RELU, int P>
__device__ __forceinline__ f16x8 mkfrag(f32x16 a) {
    float v0=a[8*P+0], v1=a[8*P+1], v2=a[8*P+2], v3=a[8*P+3];
    float v4=a[8*P+4], v5=a[8*P+5], v6=a[8*P+6], v7=a[8*P+7];
    if (RELU) {
        v0=fmaxf(v0,0.f); v1=fmaxf(v1,0.f); v2=fmaxf(v2,0.f); v3=fmaxf(v3,0.f);
        v4=fmaxf(v4,0.f); v5=fmaxf(v5,0.f); v6=fmaxf(v6,0.f); v7=fmaxf(v7,0.f);
    }
    union { unsigned int u[4]; f16x8 v; } fb;
    fb.u[0]=pkrne(v0,v1); fb.u[1]=pkrne(v2,v3); fb.u[2]=pkrne(v4,v5); fb.u[3]=pkrne(v6,v7);
    return fb.v;
}

#define MFMA(A,B,C) __builtin_amdgcn_mfma_f32_32x32x16_f16((A),(B),(C),0,0,0)
#define SB() __builtin_amdgcn_sched_barrier(0)
#define LD12(f) (*(const f16x8*)(sW12 + ((f) << 9) + (lane << 3)))
#define LDBC(f) (*(const f16x8*)(sBC  + ((f) << 9) + (lane << 3)))
#define SEL8(k, v0,v1,v2,v3,v4,v5,v6,v7) \
    ((k)==0?(v0):(k)==1?(v1):(k)==2?(v2):(k)==3?(v3): \
     (k)==4?(v4):(k)==5?(v5):(k)==6?(v6):(v7))
#define ZSEL(k) ((k)==0?bz0:(k)==1?bz1:(k)==2?bz2:(k)==3?bz3:(k)==4?bz4:(k)==5?bz5: \
                 (k)==6?bz6:(k)==7?bz7:(k)==8?bz8:(k)==9?bz9:(k)==10?bz10:(k)==11?bz11: \
                 (k)==12?bz12:(k)==13?bz13:(k)==14?bz14:bz15)
#define CVTZ(basep, ksi) ({ \
    const float* bp_ = (basep) + (ksi)*16 + hi*8; \
    float4 va_ = *(const float4*)bp_; float4 vb_ = *(const float4*)(bp_+4); \
    union { unsigned int u[4]; f16x8 v; } z_; \
    z_.u[0]=pkrne(va_.x,va_.y); z_.u[1]=pkrne(va_.z,va_.w); \
    z_.u[2]=pkrne(vb_.x,vb_.y); z_.u[3]=pkrne(vb_.z,vb_.w); z_.v; })

#define GATHER_ZA(RU, RB) do { \
    if (EF16) { \
        const f16x8* ur_ = (const f16x8*)(zu16 + (size_t)(RU)*128); \
        const f16x8* br_ = (const f16x8*)(zb16 + (size_t)(RB)*128); \
        bz0=ur_[hi];    bz1=ur_[2+hi];  bz2=ur_[4+hi];  bz3=ur_[6+hi]; \
        bz4=ur_[8+hi];  bz5=ur_[10+hi]; bz6=ur_[12+hi]; bz7=ur_[14+hi]; \
        bz8=br_[hi];    bz9=br_[2+hi];  bz10=br_[4+hi]; bz11=br_[6+hi]; \
        bz12=br_[8+hi]; bz13=br_[10+hi];bz14=br_[12+hi];bz15=br_[14+hi]; \
    } else { \
        const float* ub_ = zu + (size_t)(RU)*128; \
        const float* bb_ = zb + (size_t)(RB)*128; \
        bz0=CVTZ(ub_,0); bz1=CVTZ(ub_,1); bz2=CVTZ(ub_,2);  bz3=CVTZ(ub_,3); \
        bz4=CVTZ(ub_,4); bz5=CVTZ(ub_,5); bz6=CVTZ(ub_,6);  bz7=CVTZ(ub_,7); \
        bz8=CVTZ(bb_,0); bz9=CVTZ(bb_,1); bz10=CVTZ(bb_,2); bz11=CVTZ(bb_,3); \
        bz12=CVTZ(bb_,4);bz13=CVTZ(bb_,5);bz14=CVTZ(bb_,6); bz15=CVTZ(bb_,7); \
    } \
} while (0)

// ---------------- fused streaming edge MLP ----------------
// R6 structure at 2 waves/SIMD, with the LDS pipe (measured 75% busy, the
// wall) offloaded: bias_init (56 LDS reads/tile) -> 14 bias-column MFMAs;
// W3 (28 LDS reads/tile) -> global 1-ahead rotation (L2-hot, R6's proven
// no-spill pattern). LDS ops/tile 212 -> 142.
template<bool EF16>
__global__ __launch_bounds__(NTHR, 2) void edge_mlp(
    const int* __restrict__ eli,
    const float* __restrict__ zu, const float* __restrict__ zb,
    const f16* __restrict__ zu16, const f16* __restrict__ zb16,
    const f16* __restrict__ wsw, const float* __restrict__ b4,
    float* __restrict__ out)
{
    __shared__ f16 sW12[128*512];    // 131072 B : W1 frags 0..63, W2 frags 64..127
    __shared__ f16 sBC[14*512];      // 14336 B  : bias-column frags

    const int tid = threadIdx.x;
    const int lane = tid & 63;
    const int li = lane & 31;
    const int hi = lane >> 5;

    {
        const uint4* ws4 = (const uint4*)wsw;
        #pragma unroll
        for (int i = 0; i < 18; ++i) {
            int c = i*NTHR + tid;
            if (c < 8192)       ((uint4*)sW12)[c] = ws4[c];
            else if (c < 9088)  ((uint4*)sBC)[c - 8192] = ws4[(BCOFF/16) + (c - 8192)];
        }
    }
    __syncthreads();    // only barrier

    const bool idx64 = __all(eli[2*lane + 1] == 0);
    const f16x8* w3g = (const f16x8*)(wsw + W3OFF/2);
    const f16x8* w4g = (const f16x8*)(wsw + W4OFF/2);
    const float4 b4lo = *(const float4*)b4;
    const float  b4e  = b4[4];

    f16x8 onef = {};                  // bias-column B-frag: k==0 -> 1.0
    if (hi == 0) onef[0] = (f16)1.f;

    const int gw = (blockIdx.x*NTHR + tid) >> 6;

    int t = gw, ru = 0, rb = 0;
    f16x8 bz0,bz1,bz2,bz3,bz4,bz5,bz6,bz7,bz8,bz9,bz10,bz11,bz12,bz13,bz14,bz15;
    if (t < NT) {
        int e = t*32 + li;
        ru = idx64 ? eli[2*e]           : eli[e];
        rb = idx64 ? eli[2*(NEDGE + e)] : eli[NEDGE + e];
        GATHER_ZA(ru, rb);       // prologue gather for first tile
    }

    for (; t < NT; t += GW) {
        int tn = t + GW, run = 0, rbn = 0;
        if (tn < NT) {
            int e2 = tn*32 + li;
            run = idx64 ? eli[2*e2]           : eli[e2];
            rbn = idx64 ? eli[2*(NEDGE + e2)] : eli[NEDGE + e2];
        }

        f16x8 e30, e31;              // W3 rotation (global, 1-ahead)

        // ---- layer 1: 16 k-steps vs LDS W1, SB every 2 steps ----
        f32x16 a0 = {}, a1 = {}, a2 = {}, a3 = {};
        #pragma unroll
        for (int ks = 0; ks < 16; ++ks) {
            if (ks == 0) {           // W3 kk=0 pair: ~16 k-steps of latency cover
                e30 = w3g[(0*16 + 0)*64 + lane];
                e31 = w3g[(1*16 + 0)*64 + lane];
            }
            f16x8 bzk = ZSEL(ks);
            a0 = MFMA(LD12(0*16 + ks), bzk, a0);
            a1 = MFMA(LD12(1*16 + ks), bzk, a1);
            a2 = MFMA(LD12(2*16 + ks), bzk, a2);
            a3 = MFMA(LD12(3*16 + ks), bzk, a3);
            if (ks & 1) SB();
        }
        // W1 bias columns
        a0 = MFMA(LDBC(0), onef, a0);
        a1 = MFMA(LDBC(1), onef, a1);
        a2 = MFMA(LDBC(2), onef, a2);
        a3 = MFMA(LDBC(3), onef, a3);
        const f16x8 h1_0 = mkfrag<true,0>(a0), h1_1 = mkfrag<true,1>(a0);
        const f16x8 h1_2 = mkfrag<true,0>(a1), h1_3 = mkfrag<true,1>(a1);
        const f16x8 h1_4 = mkfrag<true,0>(a2), h1_5 = mkfrag<true,1>(a2);
        const f16x8 h1_6 = mkfrag<true,0>(a3), h1_7 = mkfrag<true,1>(a3);
        SB();

        // ---- layer 2 (two halves) fused with layer-3 accumulation ----
        f32x16 c30 = {}, c31 = {};
        f16x8 q40, q41, q42, q43;    // W4 frags (prefetched during h=1 W2 phase)
        #pragma unroll
        for (int h = 0; h < 2; ++h) {
            f32x16 b0 = {}, b1v = {}, b2v = {}, b3v = {};
            #pragma unroll
            for (int ks = 0; ks < 8; ++ks) {
                if (h == 1 && ks == 0) {
                    q40 = w4g[0*64+lane]; q41 = w4g[1*64+lane];
                    q42 = w4g[2*64+lane]; q43 = w4g[3*64+lane];
                }
                f16x8 bf = SEL8(ks, h1_0,h1_1,h1_2,h1_3,h1_4,h1_5,h1_6,h1_7);
                b0  = MFMA(LD12(64 + (h*4+0)*8 + ks), bf, b0);
                b1v = MFMA(LD12(64 + (h*4+1)*8 + ks), bf, b1v);
                b2v = MFMA(LD12(64 + (h*4+2)*8 + ks), bf, b2v);
                b3v = MFMA(LD12(64 + (h*4+3)*8 + ks), bf, b3v);
                if (ks & 1) SB();
            }
            // W2 bias columns for this half
            b0  = MFMA(LDBC(4 + h*4 + 0), onef, b0);
            b1v = MFMA(LDBC(4 + h*4 + 1), onef, b1v);
            b2v = MFMA(LDBC(4 + h*4 + 2), onef, b2v);
            b3v = MFMA(LDBC(4 + h*4 + 3), onef, b3v);
            const f16x8 h2_0 = mkfrag<true,0>(b0),  h2_1 = mkfrag<true,1>(b0);
            const f16x8 h2_2 = mkfrag<true,0>(b1v), h2_3 = mkfrag<true,1>(b1v);
            const f16x8 h2_4 = mkfrag<true,0>(b2v), h2_5 = mkfrag<true,1>(b2v);
            const f16x8 h2_6 = mkfrag<true,0>(b3v), h2_7 = mkfrag<true,1>(b3v);
            SB();
            // fused layer-3 partial accumulation; W3 global, 1-ahead rotation
            #pragma unroll
            for (int ksl = 0; ksl < 8; ++ksl) {
                const int kk = h*8 + ksl;
                f16x8 f30, f31;
                if (kk < 15) {
                    f30 = w3g[(0*16 + kk+1)*64 + lane];
                    f31 = w3g[(1*16 + kk+1)*64 + lane];
                }
                f16x8 bf2 = SEL8(ksl, h2_0,h2_1,h2_2,h2_3,h2_4,h2_5,h2_6,h2_7);
                c30 = MFMA(e30, bf2, c30);
                c31 = MFMA(e31, bf2, c31);
                if (ksl & 1) SB();
                if (kk < 15) { e30 = f30; e31 = f31; }
            }
        }
        // W3 bias columns
        c30 = MFMA(LDBC(12), onef, c30);
        c31 = MFMA(LDBC(13), onef, c31);

        // ---- issue next tile's gather into (now dead) bz regs ----
        {
            int rue = (tn < NT) ? run : ru;
            int rbe = (tn < NT) ? rbn : rb;
            GATHER_ZA(rue, rbe);
        }

        // ---- layer 3 epilogue -> layer 4 -> store ----
        const f16x8 h3_0 = mkfrag<true,0>(c30), h3_1 = mkfrag<true,1>(c30);
        const f16x8 h3_2 = mkfrag<true,0>(c31), h3_3 = mkfrag<true,1>(c31);

        f32x16 a4 = {};
        if (hi == 0) { a4[0]=b4lo.x; a4[1]=b4lo.y; a4[2]=b4lo.z; a4[3]=b4lo.w; }
        else         { a4[0]=b4e; }
        a4 = MFMA(q40, h3_0, a4);
        a4 = MFMA(q41, h3_1, a4);
        a4 = MFMA(q42, h3_2, a4);
        a4 = MFMA(q43, h3_3, a4);

        size_t eb = (size_t)(t*32 + li)*5;
        if (hi == 0) { out[eb+0]=a4[0]; out[eb+1]=a4[1]; out[eb+2]=a4[2]; out[eb+3]=a4[3]; }
        else         { out[eb+4]=a4[0]; }

        ru = run; rb = rbn;
    }
}

extern "C" void kernel_launch(void* const* d_in, const int* in_sizes, int n_in,
                              void* d_out, int out_size, void* d_ws, size_t ws_size,
                              hipStream_t stream) {
    const float* zu  = (const float*)d_in[0];
    const float* zb  = (const float*)d_in[1];
    const int*   eli = (const int*)d_in[2];
    const float* W1  = (const float*)d_in[3];
    const float* b1  = (const float*)d_in[4];
    const float* W2  = (const float*)d_in[5];
    const float* b2  = (const float*)d_in[6];
    const float* W3  = (const float*)d_in[7];
    const float* b3  = (const float*)d_in[8];
    const float* W4  = (const float*)d_in[9];
    const float* b4  = (const float*)d_in[10];
    float* out = (float*)d_out;

    f16* wsw  = (f16*)d_ws;
    f16* zu16 = (f16*)((char*)d_ws + ZUOFF);
    f16* zb16 = (f16*)((char*)d_ws + ZBOFF);

    wfrag_kernel<<<23, 512, 0, stream>>>(W1,b1,W2,b2,W3,b3,W4, (float*)d_ws);

    if (ws_size >= (size_t)WS_FULL) {
        ecvt_kernel<<<(2*(100000*128/8) + 511)/512, 512, 0, stream>>>(zu, zb, zu16, zb16);
        edge_mlp<true><<<GRID, NTHR, 0, stream>>>(eli, zu, zb, zu16, zb16, wsw, b4, out);
    } else {
        edge_mlp<false><<<GRID, NTHR, 0, stream>>>(eli, zu, zb, zu16, zb16, wsw, b4, out);
    }
}

// Round 12
// 213.557 us; speedup vs baseline: 1.2845x; 1.2845x over previous
//
#include <hip/hip_runtime.h>
#include <hip/hip_fp16.h>
#include <stdint.h>

typedef _Float16 f16;
typedef _Float16 f16x8 __attribute__((ext_vector_type(8)));
typedef _Float16 f16x16v __attribute__((ext_vector_type(16)));
typedef float    f32x16 __attribute__((ext_vector_type(16)));

#define NEDGE 1000000
#define NT    31250        // 32-edge tiles (31250*32 = 1e6, exact)
#define NTHR  512          // 8 waves/block, 2 waves/SIMD (proven optimum)
#define GRID  256
#define GW    (GRID*8)     // 2048 waves

// ---- d_ws layout (bytes); weight frags 1 KB each, sigma-row-permuted ----
#define W1OFF 0                 // 64 frags: f = nt*16+ks
#define W2OFF 65536             // 64 frags: f = nt*8+ks
#define W3OFF 131072            // 32 frags: f = nt*16+ks
#define W4OFF 163840            // 4 frags:  f = ks
#define BDOFF 167936            // biasD (legacy, unused by kernel now)
#define ZUOFF 169984
#define ZBOFF (ZUOFF + 100000*128*2)
#define WS_FULL (ZBOFF + 100000*128*2)

// sigma: swap bits 2<->3 (involution). Verified R5-R11.
__device__ __forceinline__ int sw23(int i) {
    return (i & 3) | ((i >> 1) & 4) | ((i << 1) & 8) | (i & 16);
}

// ---------------- weight fragment builder (R6 verbatim, verified) ----------------
__global__ __launch_bounds__(512) void wfrag_kernel(
    const float* __restrict__ W1, const float* __restrict__ b1,
    const float* __restrict__ W2, const float* __restrict__ b2,
    const float* __restrict__ W3, const float* __restrict__ b3,
    const float* __restrict__ W4, float* __restrict__ wsf)
{
    f16* ws = (f16*)wsf;
    const int NF = 164*64;
    int tid = blockIdx.x*512 + threadIdx.x;
    if (tid < NF) {
        int f = tid >> 6, lane = tid & 63;
        int li = lane & 31, hi = lane >> 5;
        int ip = sw23(li);
        f16 v[8];
        if (f < 64) {                       // W1 [128,256]
            int nt = f >> 4, ks = f & 15, n = nt*32 + ip;
            #pragma unroll
            for (int e = 0; e < 8; ++e) v[e] = (f16)W1[n*256 + ks*16 + hi*8 + e];
        } else if (f < 128) {               // W2 [256,128]
            int g = f-64, nt = g >> 3, ks = g & 7, n = nt*32 + ip;
            #pragma unroll
            for (int e = 0; e < 8; ++e) v[e] = (f16)W2[n*128 + ks*16 + hi*8 + e];
        } else if (f < 160) {               // W3 [64,256]
            int g = f-128, nt = g >> 4, ks = g & 15, n = nt*32 + ip;
            #pragma unroll
            for (int e = 0; e < 8; ++e) v[e] = (f16)W3[n*256 + ks*16 + hi*8 + e];
        } else {                            // W4 [5,64], rows >=5 zero, NO sigma
            int ks = f-160;
            #pragma unroll
            for (int e = 0; e < 8; ++e)
                v[e] = (li < 5) ? (f16)W4[li*64 + ks*16 + hi*8 + e] : (f16)0;
        }
        f16* d = ws + (size_t)f*512 + lane*8;
        #pragma unroll
        for (int e = 0; e < 8; ++e) d[e] = v[e];
    }
}

// ---------------- embedding f32 -> f16 ----------------
__device__ __forceinline__ void cvt8(const float* __restrict__ s, f16* __restrict__ d) {
    float4 a = ((const float4*)s)[0], b = ((const float4*)s)[1];
    union { f16 h[8]; uint4 u; } r;
    r.h[0]=(f16)a.x; r.h[1]=(f16)a.y; r.h[2]=(f16)a.z; r.h[3]=(f16)a.w;
    r.h[4]=(f16)b.x; r.h[5]=(f16)b.y; r.h[6]=(f16)b.z; r.h[7]=(f16)b.w;
    *(uint4*)d = r.u;
}
__global__ __launch_bounds__(512) void ecvt_kernel(
    const float* __restrict__ zu, const float* __restrict__ zb,
    f16* __restrict__ du, f16* __restrict__ db)
{
    const int NPER = 100000*128/8;
    int i = blockIdx.x*512 + threadIdx.x;
    if (i < NPER)          cvt8(zu + (size_t)i*8, du + (size_t)i*8);
    else if (i < 2*NPER) { int j = i - NPER; cvt8(zb + (size_t)j*8, db + (size_t)j*8); }
}

__device__ __forceinline__ unsigned int pkrne(float v0, float v1) {
    union { f16 h[2]; unsigned int u; } r;
    r.h[0] = (f16)v0; r.h[1] = (f16)v1; return r.u;
}

// lane-local epilogue (sigma makes this correct; verified R5-R11)
template<bool RELU, int P>
__device__ __forceinline__ f16x8 mkfrag(f32x16 a) {
    float v0=a[8*P+0], v1=a[8*P+1], v2=a[8*P+2], v3=a[8*P+3];
    float v4=a[8*P+4], v5=a[8*P+5], v6=a[8*P+6], v7=a[8*P+7];
    if (RELU) {
        v0=fmaxf(v0,0.f); v1=fmaxf(v1,0.f); v2=fmaxf(v2,0.f); v3=fmaxf(v3,0.f);
        v4=fmaxf(v4,0.f); v5=fmaxf(v5,0.f); v6=fmaxf(v6,0.f); v7=fmaxf(v7,0.f);
    }
    union { unsigned int u[4]; f16x8 v; } fb;
    fb.u[0]=pkrne(v0,v1); fb.u[1]=pkrne(v2,v3); fb.u[2]=pkrne(v4,v5); fb.u[3]=pkrne(v6,v7);
    return fb.v;
}

#define MFMA(A,B,C) __builtin_amdgcn_mfma_f32_32x32x16_f16((A),(B),(C),0,0,0)
#define SB() __builtin_amdgcn_sched_barrier(0)
#define LD12(f) (*(const f16x8*)(sW12 + ((f) << 9) + (lane << 3)))
#define LDT3(f) (*(const f16x8*)(sW3t + ((f) << 9) + (lane << 3)))
// bias-column A-frag built in-register (bcv pre-zeroed for hi!=0 lanes)
#define BCF(j) ({ f16x8 r_ = {}; r_[0] = bcv[j]; r_; })
#define SEL8(k, v0,v1,v2,v3,v4,v5,v6,v7) \
    ((k)==0?(v0):(k)==1?(v1):(k)==2?(v2):(k)==3?(v3): \
     (k)==4?(v4):(k)==5?(v5):(k)==6?(v6):(v7))
#define ZSEL(k) ((k)==0?bz0:(k)==1?bz1:(k)==2?bz2:(k)==3?bz3:(k)==4?bz4:(k)==5?bz5: \
                 (k)==6?bz6:(k)==7?bz7:(k)==8?bz8:(k)==9?bz9:(k)==10?bz10:(k)==11?bz11: \
                 (k)==12?bz12:(k)==13?bz13:(k)==14?bz14:bz15)
#define CVTZ(basep, ksi) ({ \
    const float* bp_ = (basep) + (ksi)*16 + hi*8; \
    float4 va_ = *(const float4*)bp_; float4 vb_ = *(const float4*)(bp_+4); \
    union { unsigned int u[4]; f16x8 v; } z_; \
    z_.u[0]=pkrne(va_.x,va_.y); z_.u[1]=pkrne(va_.z,va_.w); \
    z_.u[2]=pkrne(vb_.x,vb_.y); z_.u[3]=pkrne(vb_.z,vb_.w); z_.v; })

#define GATHER_ZA(RU, RB) do { \
    if (EF16) { \
        const f16x8* ur_ = (const f16x8*)(zu16 + (size_t)(RU)*128); \
        const f16x8* br_ = (const f16x8*)(zb16 + (size_t)(RB)*128); \
        bz0=ur_[hi];    bz1=ur_[2+hi];  bz2=ur_[4+hi];  bz3=ur_[6+hi]; \
        bz4=ur_[8+hi];  bz5=ur_[10+hi]; bz6=ur_[12+hi]; bz7=ur_[14+hi]; \
        bz8=br_[hi];    bz9=br_[2+hi];  bz10=br_[4+hi]; bz11=br_[6+hi]; \
        bz12=br_[8+hi]; bz13=br_[10+hi];bz14=br_[12+hi];bz15=br_[14+hi]; \
    } else { \
        const float* ub_ = zu + (size_t)(RU)*128; \
        const float* bb_ = zb + (size_t)(RB)*128; \
        bz0=CVTZ(ub_,0); bz1=CVTZ(ub_,1); bz2=CVTZ(ub_,2);  bz3=CVTZ(ub_,3); \
        bz4=CVTZ(ub_,4); bz5=CVTZ(ub_,5); bz6=CVTZ(ub_,6);  bz7=CVTZ(ub_,7); \
        bz8=CVTZ(bb_,0); bz9=CVTZ(bb_,1); bz10=CVTZ(bb_,2); bz11=CVTZ(bb_,3); \
        bz12=CVTZ(bb_,4);bz13=CVTZ(bb_,5);bz14=CVTZ(bb_,6); bz15=CVTZ(bb_,7); \
    } \
} while (0)

// ---------------- fused streaming edge MLP ----------------
// R6 structure verbatim (proven 172 us) with ONE change: the 56 broadcast
// bias_init LDS reads/tile are replaced by zero-init accs + 14 bias-column
// MFMAs whose A-frags are built in-register from 14 per-lane bias f16s
// (8 persistent VGPRs, loaded once). LDS ops/tile 212 -> 156.
template<bool EF16>
__global__ __launch_bounds__(NTHR, 2) void edge_mlp(
    const int* __restrict__ eli,
    const float* __restrict__ zu, const float* __restrict__ zb,
    const f16* __restrict__ zu16, const f16* __restrict__ zb16,
    const f16* __restrict__ wsw,
    const float* __restrict__ b1, const float* __restrict__ b2,
    const float* __restrict__ b3, const float* __restrict__ b4,
    float* __restrict__ out)
{
    __shared__ f16 sW12[128*512];    // 131072 B : W1 frags 0..63, W2 frags 64..127
    __shared__ f16 sW3t[28*512];     // 28672 B  : W3 frags nt*14+ks, ks<14

    const int tid = threadIdx.x;
    const int lane = tid & 63;
    const int li = lane & 31;
    const int hi = lane >> 5;

    {
        const uint4* ws4 = (const uint4*)wsw;
        #pragma unroll
        for (int i = 0; i < 16; ++i) ((uint4*)sW12)[i*NTHR + tid] = ws4[i*NTHR + tid];
        #pragma unroll
        for (int i = 0; i < 4; ++i) {
            int c = i*NTHR + tid;
            if (c < 1792) {
                int f = c >> 6, nt = f/14, ks = f - nt*14;
                ((uint4*)sW3t)[c] = ws4[(W3OFF/16) + (nt*16+ks)*64 + (c & 63)];
            }
        }
    }
    __syncthreads();    // only barrier

    const bool idx64 = __all(eli[2*lane + 1] == 0);
    const f16x8* w3g = (const f16x8*)(wsw + W3OFF/2);
    const f16x8* w4g = (const f16x8*)(wsw + W4OFF/2);
    const float4 b4lo = *(const float4*)b4;
    const float  b4e  = b4[4];

    f16x8 onef = {};                  // bias-column B-frag: k==0 -> 1.0
    if (hi == 0) onef[0] = (f16)1.f;

    // per-lane bias values (sigma-permuted rows), zeroed for hi!=0 lanes
    f16x16v bcv;
    {
        int ip = sw23(li);
        #pragma unroll
        for (int j = 0; j < 14; ++j) {
            float bvf = (j < 4)  ? b1[j*32 + ip]
                      : (j < 12) ? b2[(j-4)*32 + ip]
                                 : b3[(j-12)*32 + ip];
            bcv[j] = (hi == 0) ? (f16)bvf : (f16)0.f;
        }
        bcv[14] = (f16)0.f; bcv[15] = (f16)0.f;
    }

    const int gw = (blockIdx.x*NTHR + tid) >> 6;

    int t = gw, ru = 0, rb = 0;
    f16x8 bz0,bz1,bz2,bz3,bz4,bz5,bz6,bz7,bz8,bz9,bz10,bz11,bz12,bz13,bz14,bz15;
    if (t < NT) {
        int e = t*32 + li;
        ru = idx64 ? eli[2*e]           : eli[e];
        rb = idx64 ? eli[2*(NEDGE + e)] : eli[NEDGE + e];
        GATHER_ZA(ru, rb);       // prologue gather for first tile
    }

    for (; t < NT; t += GW) {
        int tn = t + GW, run = 0, rbn = 0;
        if (tn < NT) {
            int e2 = tn*32 + li;
            run = idx64 ? eli[2*e2]           : eli[e2];
            rbn = idx64 ? eli[2*(NEDGE + e2)] : eli[NEDGE + e2];
        }

        // ---- layer 1: 16 k-steps vs LDS W1, SB every 2 steps ----
        f32x16 a0 = {}, a1 = {}, a2 = {}, a3 = {};
        #pragma unroll
        for (int ks = 0; ks < 16; ++ks) {
            f16x8 bzk = ZSEL(ks);
            a0 = MFMA(LD12(0*16 + ks), bzk, a0);
            a1 = MFMA(LD12(1*16 + ks), bzk, a1);
            a2 = MFMA(LD12(2*16 + ks), bzk, a2);
            a3 = MFMA(LD12(3*16 + ks), bzk, a3);
            if (ks & 1) SB();
        }
        // W1 bias columns (register-built A-frags)
        a0 = MFMA(BCF(0), onef, a0);
        a1 = MFMA(BCF(1), onef, a1);
        a2 = MFMA(BCF(2), onef, a2);
        a3 = MFMA(BCF(3), onef, a3);
        const f16x8 h1_0 = mkfrag<true,0>(a0), h1_1 = mkfrag<true,1>(a0);
        const f16x8 h1_2 = mkfrag<true,0>(a1), h1_3 = mkfrag<true,1>(a1);
        const f16x8 h1_4 = mkfrag<true,0>(a2), h1_5 = mkfrag<true,1>(a2);
        const f16x8 h1_6 = mkfrag<true,0>(a3), h1_7 = mkfrag<true,1>(a3);
        SB();

        // ---- layer 2 (two halves) fused with layer-3 accumulation ----
        f32x16 c30 = {}, c31 = {};
        f16x8 g30, g31, g32, g33;    // W3 kk=14,15 (prefetched during h=1 W2 phase)
        f16x8 q40, q41, q42, q43;    // W4 frags    (prefetched during h=1 W2 phase)
        #pragma unroll
        for (int h = 0; h < 2; ++h) {
            f32x16 b0 = {}, b1v = {}, b2v = {}, b3v = {};
            #pragma unroll
            for (int ks = 0; ks < 8; ++ks) {
                if (h == 1 && ks == 0) {
                    g30 = w3g[(0*16+14)*64+lane]; g31 = w3g[(1*16+14)*64+lane];
                    g32 = w3g[(0*16+15)*64+lane]; g33 = w3g[(1*16+15)*64+lane];
                }
                if (h == 1 && ks == 1) {
                    q40 = w4g[0*64+lane]; q41 = w4g[1*64+lane];
                    q42 = w4g[2*64+lane]; q43 = w4g[3*64+lane];
                }
                f16x8 bf = SEL8(ks, h1_0,h1_1,h1_2,h1_3,h1_4,h1_5,h1_6,h1_7);
                b0  = MFMA(LD12(64 + (h*4+0)*8 + ks), bf, b0);
                b1v = MFMA(LD12(64 + (h*4+1)*8 + ks), bf, b1v);
                b2v = MFMA(LD12(64 + (h*4+2)*8 + ks), bf, b2v);
                b3v = MFMA(LD12(64 + (h*4+3)*8 + ks), bf, b3v);
                if (ks & 1) SB();
            }
            // W2 bias columns for this half
            b0  = MFMA(BCF(4 + h*4 + 0), onef, b0);
            b1v = MFMA(BCF(4 + h*4 + 1), onef, b1v);
            b2v = MFMA(BCF(4 + h*4 + 2), onef, b2v);
            b3v = MFMA(BCF(4 + h*4 + 3), onef, b3v);
            const f16x8 h2_0 = mkfrag<true,0>(b0),  h2_1 = mkfrag<true,1>(b0);
            const f16x8 h2_2 = mkfrag<true,0>(b1v), h2_3 = mkfrag<true,1>(b1v);
            const f16x8 h2_4 = mkfrag<true,0>(b2v), h2_5 = mkfrag<true,1>(b2v);
            const f16x8 h2_6 = mkfrag<true,0>(b3v), h2_7 = mkfrag<true,1>(b3v);
            SB();
            #pragma unroll
            for (int ksl = 0; ksl < 8; ++ksl) {
                f16x8 bf2 = SEL8(ksl, h2_0,h2_1,h2_2,h2_3,h2_4,h2_5,h2_6,h2_7);
                int kk = h*8 + ksl;
                f16x8 a30 = (kk < 14) ? LDT3(0*14 + kk) : ((kk == 14) ? g30 : g32);
                f16x8 a31 = (kk < 14) ? LDT3(1*14 + kk) : ((kk == 14) ? g31 : g33);
                c30 = MFMA(a30, bf2, c30);
                c31 = MFMA(a31, bf2, c31);
                if (ksl & 1) SB();
            }
        }
        // W3 bias columns
        c30 = MFMA(BCF(12), onef, c30);
        c31 = MFMA(BCF(13), onef, c31);

        // ---- issue next tile's gather into (now dead) bz regs ----
        {
            int rue = (tn < NT) ? run : ru;
            int rbe = (tn < NT) ? rbn : rb;
            GATHER_ZA(rue, rbe);
        }

        // ---- layer 3 epilogue -> layer 4 -> store ----
        const f16x8 h3_0 = mkfrag<true,0>(c30), h3_1 = mkfrag<true,1>(c30);
        const f16x8 h3_2 = mkfrag<true,0>(c31), h3_3 = mkfrag<true,1>(c31);

        f32x16 a4 = {};
        if (hi == 0) { a4[0]=b4lo.x; a4[1]=b4lo.y; a4[2]=b4lo.z; a4[3]=b4lo.w; }
        else         { a4[0]=b4e; }
        a4 = MFMA(q40, h3_0, a4);
        a4 = MFMA(q41, h3_1, a4);
        a4 = MFMA(q42, h3_2, a4);
        a4 = MFMA(q43, h3_3, a4);

        size_t eb = (size_t)(t*32 + li)*5;
        if (hi == 0) { out[eb+0]=a4[0]; out[eb+1]=a4[1]; out[eb+2]=a4[2]; out[eb+3]=a4[3]; }
        else         { out[eb+4]=a4[0]; }

        ru = run; rb = rbn;
    }
}

extern "C" void kernel_launch(void* const* d_in, const int* in_sizes, int n_in,
                              void* d_out, int out_size, void* d_ws, size_t ws_size,
                              hipStream_t stream) {
    const float* zu  = (const float*)d_in[0];
    const float* zb  = (const float*)d_in[1];
    const int*   eli = (const int*)d_in[2];
    const float* W1  = (const float*)d_in[3];
    const float* b1  = (const float*)d_in[4];
    const float* W2  = (const float*)d_in[5];
    const float* b2  = (const float*)d_in[6];
    const float* W3  = (const float*)d_in[7];
    const float* b3  = (const float*)d_in[8];
    const float* W4  = (const float*)d_in[9];
    const float* b4  = (const float*)d_in[10];
    float* out = (float*)d_out;

    f16* wsw  = (f16*)d_ws;
    f16* zu16 = (f16*)((char*)d_ws + ZUOFF);
    f16* zb16 = (f16*)((char*)d_ws + ZBOFF);

    wfrag_kernel<<<21, 512, 0, stream>>>(W1,b1,W2,b2,W3,b3,W4, (float*)d_ws);

    if (ws_size >= (size_t)WS_FULL) {
        ecvt_kernel<<<(2*(100000*128/8) + 511)/512, 512, 0, stream>>>(zu, zb, zu16, zb16);
        edge_mlp<true><<<GRID, NTHR, 0, stream>>>(eli, zu, zb, zu16, zb16, wsw,
                                                  b1, b2, b3, b4, out);
    } else {
        edge_mlp<false><<<GRID, NTHR, 0, stream>>>(eli, zu, zb, zu16, zb16, wsw,
                                                   b1, b2, b3, b4, out);
    }
}

// Round 13
// 207.758 us; speedup vs baseline: 1.3204x; 1.0279x over previous
//
#include <hip/hip_runtime.h>
#include <hip/hip_fp16.h>
#include <stdint.h>

typedef _Float16 f16;
typedef _Float16 f16x8 __attribute__((ext_vector_type(8)));
typedef float    f32x4v __attribute__((ext_vector_type(4)));
typedef float    f32x16 __attribute__((ext_vector_type(16)));

#define NEDGE 1000000
#define NT    31250        // 32-edge tiles (31250*32 = 1e6, exact)
#define NTHR  512
#define GRID  256
#define GW    (GRID*8)     // 2048 waves

// ---- d_ws layout (bytes); weight frags 1 KB each, sigma-row-permuted ----
#define W1OFF 0                 // 64 frags: f = nt*16+ks
#define W2OFF 65536             // 64 frags: f = nt*8+ks
#define W3OFF 131072            // 32 frags: f = nt*16+ks
#define W4OFF 163840            // 4 frags:  f = ks
#define BDOFF 167936            // biasD: 448 f32
#define ZUOFF 169984
#define ZBOFF (ZUOFF + 100000*128*2)
#define WS_FULL (ZBOFF + 100000*128*2)

// sigma: swap bits 2<->3 (involution). Verified R5-R12.
__device__ __forceinline__ int sw23(int i) {
    return (i & 3) | ((i >> 1) & 4) | ((i << 1) & 8) | (i & 16);
}

// ---------------- weight fragment + biasD builder (verified R5-R12) ----------------
__global__ __launch_bounds__(512) void wfrag_kernel(
    const float* __restrict__ W1, const float* __restrict__ b1,
    const float* __restrict__ W2, const float* __restrict__ b2,
    const float* __restrict__ W3, const float* __restrict__ b3,
    const float* __restrict__ W4, float* __restrict__ wsf)
{
    f16* ws = (f16*)wsf;
    const int NF = 164*64;
    int tid = blockIdx.x*512 + threadIdx.x;
    if (tid < NF) {
        int f = tid >> 6, lane = tid & 63;
        int li = lane & 31, hi = lane >> 5;
        int ip = sw23(li);
        f16 v[8];
        if (f < 64) {                       // W1 [128,256]
            int nt = f >> 4, ks = f & 15, n = nt*32 + ip;
            #pragma unroll
            for (int e = 0; e < 8; ++e) v[e] = (f16)W1[n*256 + ks*16 + hi*8 + e];
        } else if (f < 128) {               // W2 [256,128]
            int g = f-64, nt = g >> 3, ks = g & 7, n = nt*32 + ip;
            #pragma unroll
            for (int e = 0; e < 8; ++e) v[e] = (f16)W2[n*128 + ks*16 + hi*8 + e];
        } else if (f < 160) {               // W3 [64,256]
            int g = f-128, nt = g >> 4, ks = g & 15, n = nt*32 + ip;
            #pragma unroll
            for (int e = 0; e < 8; ++e) v[e] = (f16)W3[n*256 + ks*16 + hi*8 + e];
        } else {                            // W4 [5,64], rows >=5 zero, NO sigma
            int ks = f-160;
            #pragma unroll
            for (int e = 0; e < 8; ++e)
                v[e] = (li < 5) ? (f16)W4[li*64 + ks*16 + hi*8 + e] : (f16)0;
        }
        f16* d = ws + (size_t)f*512 + lane*8;
        #pragma unroll
        for (int e = 0; e < 8; ++e) d[e] = v[e];
    } else if (tid < NF + 448) {
        int j = tid - NF;
        int r = j & 15, hi = (j >> 4) & 1, nt = j >> 5;
        int n32 = (r & 7) + 8*hi + 16*(r >> 3);
        float bv = (nt < 4)  ? b1[nt*32 + n32]
                 : (nt < 12) ? b2[(nt-4)*32 + n32]
                             : b3[(nt-12)*32 + n32];
        *(float*)((char*)wsf + BDOFF + j*4) = bv;
    }
}

// ---------------- embedding f32 -> f16 ----------------
__device__ __forceinline__ void cvt8(const float* __restrict__ s, f16* __restrict__ d) {
    float4 a = ((const float4*)s)[0], b = ((const float4*)s)[1];
    union { f16 h[8]; uint4 u; } r;
    r.h[0]=(f16)a.x; r.h[1]=(f16)a.y; r.h[2]=(f16)a.z; r.h[3]=(f16)a.w;
    r.h[4]=(f16)b.x; r.h[5]=(f16)b.y; r.h[6]=(f16)b.z; r.h[7]=(f16)b.w;
    *(uint4*)d = r.u;
}
__global__ __launch_bounds__(512) void ecvt_kernel(
    const float* __restrict__ zu, const float* __restrict__ zb,
    f16* __restrict__ du, f16* __restrict__ db)
{
    const int NPER = 100000*128/8;
    int i = blockIdx.x*512 + threadIdx.x;
    if (i < NPER)          cvt8(zu + (size_t)i*8, du + (size_t)i*8);
    else if (i < 2*NPER) { int j = i - NPER; cvt8(zb + (size_t)j*8, db + (size_t)j*8); }
}

__device__ __forceinline__ unsigned int pkrne(float v0, float v1) {
    union { f16 h[2]; unsigned int u; } r;
    r.h[0] = (f16)v0; r.h[1] = (f16)v1; return r.u;
}

// lane-local epilogue (sigma makes this correct; verified R5-R12)
template<bool RELU, int P>
__device__ __forceinline__ f16x8 mkfrag(f32x16 a) {
    float v0=a[8*P+0], v1=a[8*P+1], v2=a[8*P+2], v3=a[8*P+3];
    float v4=a[8*P+4], v5=a[8*P+5], v6=a[8*P+6], v7=a[8*P+7];
    if (RELU) {
        v0=fmaxf(v0,0.f); v1=fmaxf(v1,0.f); v2=fmaxf(v2,0.f); v3=fmaxf(v3,0.f);
        v4=fmaxf(v4,0.f); v5=fmaxf(v5,0.f); v6=fmaxf(v6,0.f); v7=fmaxf(v7,0.f);
    }
    union { unsigned int u[4]; f16x8 v; } fb;
    fb.u[0]=pkrne(v0,v1); fb.u[1]=pkrne(v2,v3); fb.u[2]=pkrne(v4,v5); fb.u[3]=pkrne(v6,v7);
    return fb.v;
}

__device__ __forceinline__ f32x16 bias_init(const float* sB, int nt14, int hi) {
    const f32x4v* p = (const f32x4v*)(sB + (nt14*2 + hi)*16);
    f32x4v q0=p[0], q1=p[1], q2=p[2], q3=p[3];
    f32x16 a;
    a[0]=q0[0];  a[1]=q0[1];  a[2]=q0[2];  a[3]=q0[3];
    a[4]=q1[0];  a[5]=q1[1];  a[6]=q1[2];  a[7]=q1[3];
    a[8]=q2[0];  a[9]=q2[1];  a[10]=q2[2]; a[11]=q2[3];
    a[12]=q3[0]; a[13]=q3[1]; a[14]=q3[2]; a[15]=q3[3];
    return a;
}

#define MFMA(A,B,C) __builtin_amdgcn_mfma_f32_32x32x16_f16((A),(B),(C),0,0,0)
#define SB() __builtin_amdgcn_sched_barrier(0)
#define PRI1() __builtin_amdgcn_s_setprio(1)
#define PRI0() __builtin_amdgcn_s_setprio(0)
#define LD12(f) (*(const f16x8*)(sW12 + ((f) << 9) + (lane << 3)))
#define LDT3(f) (*(const f16x8*)(sW3t + ((f) << 9) + (lane << 3)))
#define SEL8(k, v0,v1,v2,v3,v4,v5,v6,v7) \
    ((k)==0?(v0):(k)==1?(v1):(k)==2?(v2):(k)==3?(v3): \
     (k)==4?(v4):(k)==5?(v5):(k)==6?(v6):(v7))
#define ZSEL(k) ((k)==0?bz0:(k)==1?bz1:(k)==2?bz2:(k)==3?bz3:(k)==4?bz4:(k)==5?bz5: \
                 (k)==6?bz6:(k)==7?bz7:(k)==8?bz8:(k)==9?bz9:(k)==10?bz10:(k)==11?bz11: \
                 (k)==12?bz12:(k)==13?bz13:(k)==14?bz14:bz15)
#define CVTZ(basep, ksi) ({ \
    const float* bp_ = (basep) + (ksi)*16 + hi*8; \
    float4 va_ = *(const float4*)bp_; float4 vb_ = *(const float4*)(bp_+4); \
    union { unsigned int u[4]; f16x8 v; } z_; \
    z_.u[0]=pkrne(va_.x,va_.y); z_.u[1]=pkrne(va_.z,va_.w); \
    z_.u[2]=pkrne(vb_.x,vb_.y); z_.u[3]=pkrne(vb_.z,vb_.w); z_.v; })

// ---------------- fused streaming edge MLP ----------------
// R6 structure BYTE-IDENTICAL (proven 172 us) + one change: s_setprio(1/0)
// around each MFMA burst (T5). 8 independent barrier-free waves drift across
// L1/VALU/L2 phases (attn-like regime, m191 +4-7%): a wave in its MFMA burst
// preempts co-resident waves doing mkfrag VALU / LDS reads.
template<bool EF16>
__global__ __launch_bounds__(NTHR, 2) void edge_mlp(
    const int* __restrict__ eli,
    const float* __restrict__ zu, const float* __restrict__ zb,
    const f16* __restrict__ zu16, const f16* __restrict__ zb16,
    const f16* __restrict__ wsw, const float* __restrict__ b4,
    float* __restrict__ out)
{
    __shared__ f16 sW12[128*512];    // 131072 B : W1 frags 0..63, W2 frags 64..127
    __shared__ f16 sW3t[28*512];     // 28672 B  : W3 frags nt*14+ks, ks<14
    __shared__ float sBias[448];     // 1792 B

    const int tid = threadIdx.x;
    const int lane = tid & 63;
    const int li = lane & 31;
    const int hi = lane >> 5;

    {
        const uint4* ws4 = (const uint4*)wsw;
        #pragma unroll
        for (int i = 0; i < 16; ++i) ((uint4*)sW12)[i*NTHR + tid] = ws4[i*NTHR + tid];
        #pragma unroll
        for (int i = 0; i < 4; ++i) {
            int c = i*NTHR + tid;
            if (c < 1792) {
                int f = c >> 6, nt = f/14, ks = f - nt*14;
                ((uint4*)sW3t)[c] = ws4[(W3OFF/16) + (nt*16+ks)*64 + (c & 63)];
            }
        }
        if (tid < 112) ((uint4*)sBias)[tid] = ws4[(BDOFF/16) + tid];
    }
    __syncthreads();    // only barrier

    const bool idx64 = __all(eli[2*lane + 1] == 0);
    const f16x8* w3g = (const f16x8*)(wsw + W3OFF/2);
    const f16x8* w4g = (const f16x8*)(wsw + W4OFF/2);
    const float4 b4lo = *(const float4*)b4;
    const float  b4e  = b4[4];

    const int gw = (blockIdx.x*NTHR + tid) >> 6;

    int t = gw, ru = 0, rb = 0;
    if (t < NT) {
        int e = t*32 + li;
        ru = idx64 ? eli[2*e]           : eli[e];
        rb = idx64 ? eli[2*(NEDGE + e)] : eli[NEDGE + e];
    }

    for (; t < NT; t += GW) {
        int tn = t + GW, run = 0, rbn = 0;
        if (tn < NT) {
            int e2 = tn*32 + li;
            run = idx64 ? eli[2*e2]           : eli[e2];
            rbn = idx64 ? eli[2*(NEDGE + e2)] : eli[NEDGE + e2];
        }

        // ---- gather current tile into named SSA regs (dead after L1) ----
        f16x8 bz0,bz1,bz2,bz3,bz4,bz5,bz6,bz7,bz8,bz9,bz10,bz11,bz12,bz13,bz14,bz15;
        if (EF16) {
            const f16x8* ur = (const f16x8*)(zu16 + (size_t)ru*128);
            const f16x8* br = (const f16x8*)(zb16 + (size_t)rb*128);
            bz0=ur[hi];     bz1=ur[2+hi];  bz2=ur[4+hi];  bz3=ur[6+hi];
            bz4=ur[8+hi];   bz5=ur[10+hi]; bz6=ur[12+hi]; bz7=ur[14+hi];
            bz8=br[hi];     bz9=br[2+hi];  bz10=br[4+hi]; bz11=br[6+hi];
            bz12=br[8+hi];  bz13=br[10+hi];bz14=br[12+hi];bz15=br[14+hi];
        } else {
            const float* ub = zu + (size_t)ru*128;
            const float* bb = zb + (size_t)rb*128;
            bz0=CVTZ(ub,0); bz1=CVTZ(ub,1); bz2=CVTZ(ub,2);  bz3=CVTZ(ub,3);
            bz4=CVTZ(ub,4); bz5=CVTZ(ub,5); bz6=CVTZ(ub,6);  bz7=CVTZ(ub,7);
            bz8=CVTZ(bb,0); bz9=CVTZ(bb,1); bz10=CVTZ(bb,2); bz11=CVTZ(bb,3);
            bz12=CVTZ(bb,4);bz13=CVTZ(bb,5);bz14=CVTZ(bb,6); bz15=CVTZ(bb,7);
        }

        // ---- layer 1: 16 k-steps vs LDS W1, SB every 2 steps ----
        f32x16 a0 = bias_init(sBias, 0, hi), a1 = bias_init(sBias, 1, hi);
        f32x16 a2 = bias_init(sBias, 2, hi), a3 = bias_init(sBias, 3, hi);
        #pragma unroll
        for (int ks = 0; ks < 16; ++ks) {
            f16x8 w0 = LD12(0*16 + ks), w1 = LD12(1*16 + ks),
                  w2 = LD12(2*16 + ks), w3 = LD12(3*16 + ks);
            f16x8 bzk = ZSEL(ks);
            PRI1();
            a0 = MFMA(w0, bzk, a0);
            a1 = MFMA(w1, bzk, a1);
            a2 = MFMA(w2, bzk, a2);
            a3 = MFMA(w3, bzk, a3);
            PRI0();
            if (ks & 1) SB();
        }
        const f16x8 h1_0 = mkfrag<true,0>(a0), h1_1 = mkfrag<true,1>(a0);
        const f16x8 h1_2 = mkfrag<true,0>(a1), h1_3 = mkfrag<true,1>(a1);
        const f16x8 h1_4 = mkfrag<true,0>(a2), h1_5 = mkfrag<true,1>(a2);
        const f16x8 h1_6 = mkfrag<true,0>(a3), h1_7 = mkfrag<true,1>(a3);
        SB();

        // ---- layer 2 (two halves) fused with layer-3 accumulation ----
        f32x16 c30 = bias_init(sBias, 12, hi), c31 = bias_init(sBias, 13, hi);
        #pragma unroll
        for (int h = 0; h < 2; ++h) {
            f32x16 b0  = bias_init(sBias, 4 + h*4 + 0, hi);
            f32x16 b1v = bias_init(sBias, 4 + h*4 + 1, hi);
            f32x16 b2v = bias_init(sBias, 4 + h*4 + 2, hi);
            f32x16 b3v = bias_init(sBias, 4 + h*4 + 3, hi);
            #pragma unroll
            for (int ks = 0; ks < 8; ++ks) {
                f16x8 d0 = LD12(64 + (h*4+0)*8 + ks), d1 = LD12(64 + (h*4+1)*8 + ks),
                      d2 = LD12(64 + (h*4+2)*8 + ks), d3 = LD12(64 + (h*4+3)*8 + ks);
                f16x8 bf = SEL8(ks, h1_0,h1_1,h1_2,h1_3,h1_4,h1_5,h1_6,h1_7);
                PRI1();
                b0  = MFMA(d0, bf, b0);
                b1v = MFMA(d1, bf, b1v);
                b2v = MFMA(d2, bf, b2v);
                b3v = MFMA(d3, bf, b3v);
                PRI0();
                if (ks & 1) SB();
            }
            const f16x8 h2_0 = mkfrag<true,0>(b0),  h2_1 = mkfrag<true,1>(b0);
            const f16x8 h2_2 = mkfrag<true,0>(b1v), h2_3 = mkfrag<true,1>(b1v);
            const f16x8 h2_4 = mkfrag<true,0>(b2v), h2_5 = mkfrag<true,1>(b2v);
            const f16x8 h2_6 = mkfrag<true,0>(b3v), h2_7 = mkfrag<true,1>(b3v);
            SB();
            #pragma unroll
            for (int ksl = 0; ksl < 8; ++ksl) {
                f16x8 bf2 = SEL8(ksl, h2_0,h2_1,h2_2,h2_3,h2_4,h2_5,h2_6,h2_7);
                int kk = h*8 + ksl;
                f16x8 a30 = (kk < 14) ? LDT3(0*14 + kk) : w3g[(0*16 + kk)*64 + lane];
                f16x8 a31 = (kk < 14) ? LDT3(1*14 + kk) : w3g[(1*16 + kk)*64 + lane];
                PRI1();
                c30 = MFMA(a30, bf2, c30);
                c31 = MFMA(a31, bf2, c31);
                PRI0();
                if (ksl & 1) SB();
            }
        }

        // ---- layer 3 epilogue -> layer 4 -> store ----
        const f16x8 h3_0 = mkfrag<true,0>(c30), h3_1 = mkfrag<true,1>(c30);
        const f16x8 h3_2 = mkfrag<true,0>(c31), h3_3 = mkfrag<true,1>(c31);

        f32x16 a4 = {};
        if (hi == 0) { a4[0]=b4lo.x; a4[1]=b4lo.y; a4[2]=b4lo.z; a4[3]=b4lo.w; }
        else         { a4[0]=b4e; }
        PRI1();
        a4 = MFMA(w4g[0*64+lane], h3_0, a4);
        a4 = MFMA(w4g[1*64+lane], h3_1, a4);
        a4 = MFMA(w4g[2*64+lane], h3_2, a4);
        a4 = MFMA(w4g[3*64+lane], h3_3, a4);
        PRI0();

        size_t eb = (size_t)(t*32 + li)*5;
        if (hi == 0) { out[eb+0]=a4[0]; out[eb+1]=a4[1]; out[eb+2]=a4[2]; out[eb+3]=a4[3]; }
        else         { out[eb+4]=a4[0]; }

        ru = run; rb = rbn;
    }
}

extern "C" void kernel_launch(void* const* d_in, const int* in_sizes, int n_in,
                              void* d_out, int out_size, void* d_ws, size_t ws_size,
                              hipStream_t stream) {
    const float* zu  = (const float*)d_in[0];
    const float* zb  = (const float*)d_in[1];
    const int*   eli = (const int*)d_in[2];
    const float* W1  = (const float*)d_in[3];
    const float* b1  = (const float*)d_in[4];
    const float* W2  = (const float*)d_in[5];
    const float* b2  = (const float*)d_in[6];
    const float* W3  = (const float*)d_in[7];
    const float* b3  = (const float*)d_in[8];
    const float* W4  = (const float*)d_in[9];
    const float* b4  = (const float*)d_in[10];
    float* out = (float*)d_out;

    f16* wsw  = (f16*)d_ws;
    f16* zu16 = (f16*)((char*)d_ws + ZUOFF);
    f16* zb16 = (f16*)((char*)d_ws + ZBOFF);

    wfrag_kernel<<<22, 512, 0, stream>>>(W1,b1,W2,b2,W3,b3,W4, (float*)d_ws);

    if (ws_size >= (size_t)WS_FULL) {
        ecvt_kernel<<<(2*(100000*128/8) + 511)/512, 512, 0, stream>>>(zu, zb, zu16, zb16);
        edge_mlp<true><<<GRID, NTHR, 0, stream>>>(eli, zu, zb, zu16, zb16, wsw, b4, out);
    } else {
        edge_mlp<false><<<GRID, NTHR, 0, stream>>>(eli, zu, zb, zu16, zb16, wsw, b4, out);
    }
}